// Round 2
// baseline (339.455 us; speedup 1.0000x reference)
//
#include <hip/hip_runtime.h>
#include <math.h>

#define HS 64
#define NE 128
#define TSEQ 2048

#define FMA4(acc, s, vec) { (acc).x += (s)*(vec).x; (acc).y += (s)*(vec).y; (acc).z += (s)*(vec).z; (acc).w += (s)*(vec).w; }

// ---------------- QKV projection ----------------
// 32 rows per block, 256 threads: thread (rg=tid>>4, hg=tid&15) computes rows
// {rg*2, rg*2+1} x h in [hg*4, hg*4+4) for all three matrices.
// q is pre-scaled by 1/sqrt(64) = 0.125.
__global__ __launch_bounds__(256) void qkv_proj(
    const float* __restrict__ x,
    const float* __restrict__ Wk, const float* __restrict__ bk,
    const float* __restrict__ Wq, const float* __restrict__ bq,
    const float* __restrict__ Wv, const float* __restrict__ bv,
    float* __restrict__ qo, float* __restrict__ ko, float* __restrict__ vo)
{
    const int tid = threadIdx.x;
    const int rg = tid >> 4;
    const int hg = tid & 15;
    const size_t row0 = (size_t)blockIdx.x * 32 + (size_t)rg * 2;
    const int h0 = hg << 2;

    float4 aq0 = *(const float4*)(bq + h0);
    float4 aq1 = aq0;
    float4 ak0 = *(const float4*)(bk + h0);
    float4 ak1 = ak0;
    float4 av0 = *(const float4*)(bv + h0);
    float4 av1 = av0;

    const float* xr0 = x + row0 * NE;
    const float* xr1 = xr0 + NE;

    for (int c4 = 0; c4 < NE; c4 += 4) {
        float4 x0 = *(const float4*)(xr0 + c4);
        float4 x1 = *(const float4*)(xr1 + c4);
#pragma unroll
        for (int cc = 0; cc < 4; ++cc) {
            const int c = c4 + cc;
            float4 wgq = *(const float4*)(Wq + c * HS + h0);
            float4 wgk = *(const float4*)(Wk + c * HS + h0);
            float4 wgv = *(const float4*)(Wv + c * HS + h0);
            const float s0 = (&x0.x)[cc];
            const float s1 = (&x1.x)[cc];
            FMA4(aq0, s0, wgq); FMA4(aq1, s1, wgq);
            FMA4(ak0, s0, wgk); FMA4(ak1, s1, wgk);
            FMA4(av0, s0, wgv); FMA4(av1, s1, wgv);
        }
    }

    const float sc = 0.125f;  // 64^-0.5 folded into q
    aq0.x *= sc; aq0.y *= sc; aq0.z *= sc; aq0.w *= sc;
    aq1.x *= sc; aq1.y *= sc; aq1.z *= sc; aq1.w *= sc;

    *(float4*)(qo + row0 * HS + h0) = aq0;
    *(float4*)(qo + (row0 + 1) * HS + h0) = aq1;
    *(float4*)(ko + row0 * HS + h0) = ak0;
    *(float4*)(ko + (row0 + 1) * HS + h0) = ak1;
    *(float4*)(vo + row0 * HS + h0) = av0;
    *(float4*)(vo + (row0 + 1) * HS + h0) = av1;
}

// ---------------- Flash attention (fp32 vector) ----------------
// One block per (batch, 64-query tile). 256 threads: (i=tid>>4, j=tid&15),
// thread owns score/output block rows 4i..4i+3, cols 4j..4j+3.
// LDS: Q padded [64][68]; K (later aliased by P) swizzled [64][64]; V [64][64].
__global__ __launch_bounds__(256) void attn(
    const float* __restrict__ q, const float* __restrict__ k,
    const float* __restrict__ v, float* __restrict__ out)
{
    __shared__ float Qs[64 * 68];
    __shared__ float KP[64 * 64];   // K tile, then aliased by P
    __shared__ float Vs[64 * 64];

    const int tid = threadIdx.x;
    const int n = blockIdx.x;
    // complement pairing: blocks n and n+256 have qt summing to 31 -> balanced CUs
    const int u = n & 255;
    const int b = u >> 4;
    const int r16 = u & 15;
    const int qt = (n < 256) ? r16 : (31 - r16);
    const int t0 = qt << 6;
    const size_t base = (size_t)b * TSEQ;

    const int i = tid >> 4;
    const int j = tid & 15;

    // stage Q tile (visible after first in-loop barrier)
#pragma unroll
    for (int l4 = 0; l4 < 4; ++l4) {
        const int flat = l4 * 256 + tid;
        const int row = flat >> 4;
        const int c4 = (flat & 15) << 2;
        *(float4*)&Qs[row * 68 + c4] =
            *(const float4*)(q + (base + t0 + row) * HS + c4);
    }

    float m[4], lsum[4], o[4][4];
#pragma unroll
    for (int a = 0; a < 4; ++a) {
        m[a] = -INFINITY;
        lsum[a] = 0.f;
#pragma unroll
        for (int bb = 0; bb < 4; ++bb) o[a][bb] = 0.f;
    }

    const int nt = qt + 1;
    for (int tile = 0; tile < nt; ++tile) {
        const int s0 = tile << 6;
        __syncthreads();  // prior-iteration reads of KP/Vs complete
        // stage K (xor-swizzled columns) and V
#pragma unroll
        for (int l4 = 0; l4 < 4; ++l4) {
            const int flat = l4 * 256 + tid;
            const int row = flat >> 4;
            const int c4 = flat & 15;
            const size_t g = (base + s0 + row) * HS + (c4 << 2);
            float4 kvv = *(const float4*)(k + g);
            *(float4*)&KP[row * 64 + ((c4 ^ (row >> 2)) << 2)] = kvv;
            float4 vvv = *(const float4*)(v + g);
            *(float4*)&Vs[row * 64 + (c4 << 2)] = vvv;
        }
        __syncthreads();

        // ---- S = Q K^T (q pre-scaled) ----
        float sacc[4][4];
#pragma unroll
        for (int a = 0; a < 4; ++a)
#pragma unroll
            for (int bb = 0; bb < 4; ++bb) sacc[a][bb] = 0.f;

        for (int h4 = 0; h4 < 16; ++h4) {
            float4 qa[4], kb[4];
#pragma unroll
            for (int a = 0; a < 4; ++a)
                qa[a] = *(const float4*)&Qs[(4 * i + a) * 68 + (h4 << 2)];
#pragma unroll
            for (int bb = 0; bb < 4; ++bb)
                kb[bb] = *(const float4*)&KP[(4 * j + bb) * 64 + ((h4 ^ j) << 2)];
#pragma unroll
            for (int a = 0; a < 4; ++a)
#pragma unroll
                for (int bb = 0; bb < 4; ++bb)
                    sacc[a][bb] += qa[a].x * kb[bb].x + qa[a].y * kb[bb].y
                                 + qa[a].z * kb[bb].z + qa[a].w * kb[bb].w;
        }

        // causal mask (diagonal tile only)
        if (s0 == t0) {
#pragma unroll
            for (int a = 0; a < 4; ++a)
#pragma unroll
                for (int bb = 0; bb < 4; ++bb)
                    if (4 * j + bb > 4 * i + a) sacc[a][bb] = -INFINITY;
        }

        // ---- online softmax (rows live in 16-lane groups) ----
        float pr[4][4];
#pragma unroll
        for (int a = 0; a < 4; ++a) {
            float mx = fmaxf(fmaxf(sacc[a][0], sacc[a][1]),
                             fmaxf(sacc[a][2], sacc[a][3]));
            mx = fmaxf(mx, __shfl_xor(mx, 1));
            mx = fmaxf(mx, __shfl_xor(mx, 2));
            mx = fmaxf(mx, __shfl_xor(mx, 4));
            mx = fmaxf(mx, __shfl_xor(mx, 8));
            const float mnew = fmaxf(m[a], mx);
            const float alpha = __expf(m[a] - mnew);  // exp(-inf)=0 first tile
            m[a] = mnew;
            float rs = 0.f;
#pragma unroll
            for (int bb = 0; bb < 4; ++bb) {
                pr[a][bb] = __expf(sacc[a][bb] - mnew);  // masked -> 0
                rs += pr[a][bb];
            }
            rs += __shfl_xor(rs, 1);
            rs += __shfl_xor(rs, 2);
            rs += __shfl_xor(rs, 4);
            rs += __shfl_xor(rs, 8);
            lsum[a] = lsum[a] * alpha + rs;
#pragma unroll
            for (int bb = 0; bb < 4; ++bb) o[a][bb] *= alpha;
        }

        __syncthreads();  // all K reads done before P overwrites KP
#pragma unroll
        for (int a = 0; a < 4; ++a) {
            float4 pv = make_float4(pr[a][0], pr[a][1], pr[a][2], pr[a][3]);
            *(float4*)&KP[(4 * i + a) * 64 + ((j ^ i) << 2)] = pv;
        }
        __syncthreads();  // P visible

        // ---- O += P V ----
        for (int s4 = 0; s4 < 16; ++s4) {
            float4 pa[4], vb[4];
#pragma unroll
            for (int a = 0; a < 4; ++a)
                pa[a] = *(const float4*)&KP[(4 * i + a) * 64 + ((s4 ^ i) << 2)];
#pragma unroll
            for (int ss = 0; ss < 4; ++ss)
                vb[ss] = *(const float4*)&Vs[(4 * s4 + ss) * 64 + (j << 2)];
#pragma unroll
            for (int a = 0; a < 4; ++a) {
#pragma unroll
                for (int ss = 0; ss < 4; ++ss) {
                    const float p = (&pa[a].x)[ss];
                    o[a][0] += p * vb[ss].x;
                    o[a][1] += p * vb[ss].y;
                    o[a][2] += p * vb[ss].z;
                    o[a][3] += p * vb[ss].w;
                }
            }
        }
    }

#pragma unroll
    for (int a = 0; a < 4; ++a) {
        const float inv = 1.0f / lsum[a];
        float4 res = make_float4(o[a][0] * inv, o[a][1] * inv,
                                 o[a][2] * inv, o[a][3] * inv);
        *(float4*)(out + (base + t0 + 4 * i + a) * HS + (j << 2)) = res;
    }
}

extern "C" void kernel_launch(void* const* d_in, const int* in_sizes, int n_in,
                              void* d_out, int out_size, void* d_ws, size_t ws_size,
                              hipStream_t stream) {
    const float* x  = (const float*)d_in[0];
    const float* Wk = (const float*)d_in[1];
    const float* bk = (const float*)d_in[2];
    const float* Wq = (const float*)d_in[3];
    const float* bq = (const float*)d_in[4];
    const float* Wv = (const float*)d_in[5];
    const float* bv = (const float*)d_in[6];
    float* outp = (float*)d_out;

    const size_t elems = (size_t)16 * TSEQ * HS;  // 2M per tensor
    float* qb = (float*)d_ws;
    float* kb = qb + elems;
    float* vb = kb + elems;

    qkv_proj<<<1024, 256, 0, stream>>>(x, Wk, bk, Wq, bq, Wv, bv, qb, kb, vb);
    attn<<<512, 256, 0, stream>>>(qb, kb, vb, outp);
}

// Round 3
// 173.673 us; speedup vs baseline: 1.9546x; 1.9546x over previous
//
#include <hip/hip_runtime.h>
#include <math.h>

#define HS 64
#define NE 128
#define TSEQ 2048
#define SK 72   // padded LDS row stride in bf16 elems (144B = 36 banks -> 2-way max)

typedef short s8v __attribute__((ext_vector_type(8)));   // 8 bf16 (4 VGPRs) MFMA A/B frag
typedef float f4v __attribute__((ext_vector_type(4)));   // 4 fp32 MFMA C/D frag

#define FMA4(acc, s, vec) { (acc).x += (s)*(vec).x; (acc).y += (s)*(vec).y; (acc).z += (s)*(vec).z; (acc).w += (s)*(vec).w; }

__device__ __forceinline__ unsigned short f2bf(float f) {
    unsigned int u = __float_as_uint(f);
    u += 0x7FFFu + ((u >> 16) & 1u);   // RNE (no NaN inputs here)
    return (unsigned short)(u >> 16);
}

// ---------------- QKV projection (fp32 compute, bf16 outputs) ----------------
// q pre-scaled by 0.125 * log2(e) so attention softmax runs in exp2 domain.
// v is written TRANSPOSED: vt[b][dim][t], dim-major, for the PV MFMA A-operand.
__global__ __launch_bounds__(256) void qkv_proj(
    const float* __restrict__ x,
    const float* __restrict__ Wk, const float* __restrict__ bk,
    const float* __restrict__ Wq, const float* __restrict__ bq,
    const float* __restrict__ Wv, const float* __restrict__ bv,
    unsigned short* __restrict__ qo, unsigned short* __restrict__ ko,
    unsigned short* __restrict__ vt)
{
    const int tid = threadIdx.x;
    const int rg = tid >> 4;
    const int hg = tid & 15;
    const size_t row0 = (size_t)blockIdx.x * 32 + (size_t)rg * 2;
    const int h0 = hg << 2;

    float4 aq0 = *(const float4*)(bq + h0);
    float4 aq1 = aq0;
    float4 ak0 = *(const float4*)(bk + h0);
    float4 ak1 = ak0;
    float4 av0 = *(const float4*)(bv + h0);
    float4 av1 = av0;

    const float* xr0 = x + row0 * NE;
    const float* xr1 = xr0 + NE;

    for (int c4 = 0; c4 < NE; c4 += 4) {
        float4 x0 = *(const float4*)(xr0 + c4);
        float4 x1 = *(const float4*)(xr1 + c4);
#pragma unroll
        for (int cc = 0; cc < 4; ++cc) {
            const int c = c4 + cc;
            float4 wgq = *(const float4*)(Wq + c * HS + h0);
            float4 wgk = *(const float4*)(Wk + c * HS + h0);
            float4 wgv = *(const float4*)(Wv + c * HS + h0);
            const float s0 = (&x0.x)[cc];
            const float s1 = (&x1.x)[cc];
            FMA4(aq0, s0, wgq); FMA4(aq1, s1, wgq);
            FMA4(ak0, s0, wgk); FMA4(ak1, s1, wgk);
            FMA4(av0, s0, wgv); FMA4(av1, s1, wgv);
        }
    }

    const float sc = 0.18033688f;  // 64^-0.5 * log2(e)
    ushort4 uq0, uq1, uk0, uk1;
    uq0.x = f2bf(aq0.x * sc); uq0.y = f2bf(aq0.y * sc); uq0.z = f2bf(aq0.z * sc); uq0.w = f2bf(aq0.w * sc);
    uq1.x = f2bf(aq1.x * sc); uq1.y = f2bf(aq1.y * sc); uq1.z = f2bf(aq1.z * sc); uq1.w = f2bf(aq1.w * sc);
    uk0.x = f2bf(ak0.x); uk0.y = f2bf(ak0.y); uk0.z = f2bf(ak0.z); uk0.w = f2bf(ak0.w);
    uk1.x = f2bf(ak1.x); uk1.y = f2bf(ak1.y); uk1.z = f2bf(ak1.z); uk1.w = f2bf(ak1.w);

    *(ushort4*)(qo + row0 * HS + h0)       = uq0;
    *(ushort4*)(qo + (row0 + 1) * HS + h0) = uq1;
    *(ushort4*)(ko + row0 * HS + h0)       = uk0;
    *(ushort4*)(ko + (row0 + 1) * HS + h0) = uk1;

    const size_t bidx = row0 >> 11;     // batch (blocks of 32 rows never straddle)
    const size_t trow = row0 & 2047;
#pragma unroll
    for (int cc = 0; cc < 4; ++cc) {
        const size_t r = (bidx * HS + h0 + cc) * TSEQ + trow;
        vt[r]     = f2bf((&av0.x)[cc]);
        vt[r + 1] = f2bf((&av1.x)[cc]);
    }
}

// ---------------- Flash attention (bf16 MFMA) ----------------
// Block = 4 waves, 64 q-rows (16/wave). Iterate 64-key tiles.
// Per wave/iter: S^T = K·Q^T (8 mfma_16x16x32_bf16), online softmax (one q-row
// per lane in S^T C-layout), P -> LDS (b64 writes / b128 reads), O^T = V^T·P^T
// (8 mfma). All LDS rows padded to SK=72 bf16 -> <=2-way bank aliasing (free).
__global__ __launch_bounds__(256) void attn(
    const unsigned short* __restrict__ qb,
    const unsigned short* __restrict__ kb,
    const unsigned short* __restrict__ vtb,
    float* __restrict__ out)
{
    __shared__ unsigned short Ks[64 * SK];     // [key][dim]
    __shared__ unsigned short Vs[64 * SK];     // [dim][key]
    __shared__ unsigned short Ps[4 * 16 * SK]; // per-wave [qrow][key]

    const int tid = threadIdx.x;
    const int w = tid >> 6;
    const int lane = tid & 63;
    const int quad = lane >> 4;
    const int li = lane & 15;

    const int n = blockIdx.x;
    const int u = n & 255;
    const int b = u >> 4;
    const int r16 = u & 15;
    const int qt = (n < 256) ? r16 : (31 - r16);  // complement pairing balance
    const int t0 = qt << 6;
    const size_t base = (size_t)b * TSEQ;

    const int qrow = t0 + w * 16 + li;   // this lane's q-row (S^T col = li)

    // Q B-frags (regs, once): B[k=dim=quad*8+j][n=qrow=li]
    const unsigned short* qrp = qb + (base + qrow) * HS + quad * 8;
    s8v qf0 = *(const s8v*)qrp;
    s8v qf1 = *(const s8v*)(qrp + 32);

    f4v c_o[4];
#pragma unroll
    for (int f = 0; f < 4; ++f) c_o[f] = (f4v){0.f, 0.f, 0.f, 0.f};
    float m = -INFINITY, lsum = 0.f;

    // staging: thread -> row kr, 32B chunk kc
    const int kr = tid >> 2;
    const int kc = (tid & 3) << 4;
    unsigned short* ksw = &Ks[kr * SK + kc];
    unsigned short* vsw = &Vs[kr * SK + kc];
    const unsigned short* gkrow = kb + (base + kr) * HS + kc;
    const unsigned short* gvrow = vtb + ((size_t)b * HS + kr) * TSEQ + kc;

    unsigned short* prow = &Ps[(w * 16 + li) * SK];

    for (int tile = 0; tile <= qt; ++tile) {
        const int s0 = tile << 6;
        __syncthreads();   // prior iter's LDS reads done
        {
            const unsigned short* gk = gkrow + (size_t)s0 * HS;
            s8v ka = *(const s8v*)gk;
            s8v kb2 = *(const s8v*)(gk + 8);
            const unsigned short* gv = gvrow + s0;
            s8v va = *(const s8v*)gv;
            s8v vb2 = *(const s8v*)(gv + 8);
            *(s8v*)ksw = ka; *(s8v*)(ksw + 8) = kb2;
            *(s8v*)vsw = va; *(s8v*)(vsw + 8) = vb2;
        }
        __syncthreads();

        // ---- S^T = K · Q^T ----
        f4v cst[4];
#pragma unroll
        for (int kt = 0; kt < 4; ++kt) cst[kt] = (f4v){0.f, 0.f, 0.f, 0.f};
#pragma unroll
        for (int kt = 0; kt < 4; ++kt) {
            const unsigned short* krow = &Ks[(kt * 16 + li) * SK + quad * 8];
            s8v k0 = *(const s8v*)krow;
            s8v k1 = *(const s8v*)(krow + 32);
            cst[kt] = __builtin_amdgcn_mfma_f32_16x16x32_bf16(k0, qf0, cst[kt], 0, 0, 0);
            cst[kt] = __builtin_amdgcn_mfma_f32_16x16x32_bf16(k1, qf1, cst[kt], 0, 0, 0);
        }

        // causal mask (diagonal tile only): key = s0 + kt*16 + quad*4 + r
        if (tile == qt) {
#pragma unroll
            for (int kt = 0; kt < 4; ++kt)
#pragma unroll
                for (int r = 0; r < 4; ++r)
                    if (s0 + kt * 16 + quad * 4 + r > qrow) cst[kt][r] = -INFINITY;
        }

        // ---- online softmax (exp2 domain; q pre-scaled by log2e/8) ----
        float mx = -INFINITY;
#pragma unroll
        for (int kt = 0; kt < 4; ++kt)
#pragma unroll
            for (int r = 0; r < 4; ++r) mx = fmaxf(mx, cst[kt][r]);
        mx = fmaxf(mx, __shfl_xor(mx, 16));
        mx = fmaxf(mx, __shfl_xor(mx, 32));
        const float mnew = fmaxf(m, mx);
        const float alpha = exp2f(m - mnew);
        m = mnew;
        float p[4][4];
        float rs = 0.f;
#pragma unroll
        for (int kt = 0; kt < 4; ++kt)
#pragma unroll
            for (int r = 0; r < 4; ++r) {
                p[kt][r] = exp2f(cst[kt][r] - mnew);
                rs += p[kt][r];
            }
        rs += __shfl_xor(rs, 16);
        rs += __shfl_xor(rs, 32);
        lsum = lsum * alpha + rs;
#pragma unroll
        for (int f = 0; f < 4; ++f) {
            c_o[f][0] *= alpha; c_o[f][1] *= alpha;
            c_o[f][2] *= alpha; c_o[f][3] *= alpha;
        }

        // ---- P -> LDS (wave-private; 4 consecutive keys per C reg group = b64)
#pragma unroll
        for (int kt = 0; kt < 4; ++kt) {
            ushort4 pk;
            pk.x = f2bf(p[kt][0]); pk.y = f2bf(p[kt][1]);
            pk.z = f2bf(p[kt][2]); pk.w = f2bf(p[kt][3]);
            *(ushort4*)(prow + kt * 16 + quad * 4) = pk;
        }

        // ---- O^T += V^T · P^T ----
        s8v pf0 = *(const s8v*)(prow + quad * 8);
        s8v pf1 = *(const s8v*)(prow + 32 + quad * 8);
#pragma unroll
        for (int f = 0; f < 4; ++f) {
            const unsigned short* vrow = &Vs[(f * 16 + li) * SK + quad * 8];
            s8v v0 = *(const s8v*)vrow;
            s8v v1 = *(const s8v*)(vrow + 32);
            c_o[f] = __builtin_amdgcn_mfma_f32_16x16x32_bf16(v0, pf0, c_o[f], 0, 0, 0);
            c_o[f] = __builtin_amdgcn_mfma_f32_16x16x32_bf16(v1, pf1, c_o[f], 0, 0, 0);
        }
    }

    // epilogue: O^T C-frag -> out[b][t][dim], 4 contiguous dims per frag
    const float inv = 1.0f / lsum;
    float* orow = out + (base + qrow) * HS + quad * 4;
#pragma unroll
    for (int f = 0; f < 4; ++f) {
        f4v res = c_o[f];
        res[0] *= inv; res[1] *= inv; res[2] *= inv; res[3] *= inv;
        *(f4v*)(orow + f * 16) = res;
    }
}

extern "C" void kernel_launch(void* const* d_in, const int* in_sizes, int n_in,
                              void* d_out, int out_size, void* d_ws, size_t ws_size,
                              hipStream_t stream) {
    const float* x  = (const float*)d_in[0];
    const float* Wk = (const float*)d_in[1];
    const float* bk = (const float*)d_in[2];
    const float* Wq = (const float*)d_in[3];
    const float* bq = (const float*)d_in[4];
    const float* Wv = (const float*)d_in[5];
    const float* bv = (const float*)d_in[6];
    float* outp = (float*)d_out;

    const size_t elems = (size_t)16 * TSEQ * HS;  // 2M per tensor
    unsigned short* qbuf = (unsigned short*)d_ws;
    unsigned short* kbuf = qbuf + elems;
    unsigned short* vbuf = kbuf + elems;          // transposed [b][dim][t]

    qkv_proj<<<1024, 256, 0, stream>>>(x, Wk, bk, Wq, bq, Wv, bv, qbuf, kbuf, vbuf);
    attn<<<512, 256, 0, stream>>>(qbuf, kbuf, vbuf, outp);
}